// Round 6
// baseline (112.382 us; speedup 1.0000x reference)
//
#include <hip/hip_runtime.h>
#include <hip/hip_bf16.h>

#define NB 128
#define NS 101
#define NW 1024
#define OH 200
#define OW 200
#define EPS 1034   // epi row stride (floats): 4*EPS % 128B -> 2-way (free) dump

typedef __bf16 bf16x8 __attribute__((ext_vector_type(8)));
typedef float f32x4 __attribute__((ext_vector_type(4)));

__device__ __forceinline__ void gload_lds16(const void* gsrc, void* ldst) {
    __builtin_amdgcn_global_load_lds(
        (const __attribute__((address_space(1))) void*)gsrc,
        (__attribute__((address_space(3))) void*)ldst, 16, 0, 0);
}

// prep: per batch, build xRsh image (8 shifted copies of reversed padded
// signal, bf16, 2056 ushorts per copy) + Kbf[112][1024] bf16 (rows>=NS zero).
__global__ __launch_bounds__(256) void prep_kernel(
        const float* __restrict__ x, const float* __restrict__ K,
        ushort* __restrict__ Kbf, ushort* __restrict__ xRsh) {
    const int b = blockIdx.x;
    const int tid = threadIdx.x;
    const float* xb = x + (size_t)b * NW;
    ushort* dst = xRsh + (size_t)b * 16448;
    for (int idx = tid; idx < 2056; idx += 256) {
        const int d = idx / 257;
        const int i0 = (idx % 257) * 8;
        union { ushort us[8]; uint4 v; } pk;
        #pragma unroll
        for (int j = 0; j < 8; ++j) {
            const int q = i0 + j + d;
            float f = (q >= 512 && q < 1536) ? xb[1535 - q] : 0.0f;
            __hip_bfloat16 h = __float2bfloat16(f);
            pk.us[j] = reinterpret_cast<const ushort&>(h);
        }
        *(uint4*)(dst + d * 2056 + i0) = pk.v;
    }
    if (b < 112) {
        const int c = tid * 4;
        float4 v = make_float4(0.f, 0.f, 0.f, 0.f);
        if (b < NS) v = *(const float4*)(K + (size_t)b * NW + c);
        ushort4 o; __hip_bfloat16 h;
        h = __float2bfloat16(v.x); o.x = reinterpret_cast<const ushort&>(h);
        h = __float2bfloat16(v.y); o.y = reinterpret_cast<const ushort&>(h);
        h = __float2bfloat16(v.z); o.z = reinterpret_cast<const ushort&>(h);
        h = __float2bfloat16(v.w); o.w = reinterpret_cast<const ushort&>(h);
        *(ushort4*)(Kbf + (size_t)b * NW + c) = o;
    }
}

// conv body: one 16-row t-tile, active s in [LO,HI] (compile-time).
// 8 waves x 128 w each. A from global (L2), B from xSh ring.
template<int LO, int HI>
__device__ __forceinline__ void conv_body(
        const int t, const int b,
        const ushort* __restrict__ Kbf, const ushort* __restrict__ xRsh,
        __hip_bfloat16* __restrict__ tmp, float* __restrict__ mm,
        ushort* xSh, float* epi, float* smn, float* smx) {
    const int tid = threadIdx.x;
    const int wv = tid >> 6, lane = tid & 63, n = lane & 15, g = lane >> 4;

    // stage xSh: pure linear copy from prep-built global image
    {
        const ushort* src = xRsh + (size_t)b * 16448;
        for (int idx = tid; idx < 2056; idx += 512)
            gload_lds16(src + (size_t)idx * 8, xSh + idx * 8);
    }
    __syncthreads();   // drains vmcnt for global_load_lds

    // B-ring base: lane reads xR[q0..q0+7] from shifted copy dlt=(7-n)&7,
    // 16B-aligned by construction (r2-r5 verified formulas)
    const int dlt = (7 - n) & 7;
    const int wbase = wv * 128;
    const ushort* bp = xSh + dlt * 2056 + (1023 - wbase - n + 8 * g - dlt);
    const ushort* ap = Kbf + (size_t)(16 * t + n) * NW + 8 * g;

    f32x4 acc[8];
    #pragma unroll
    for (int nt = 0; nt < 8; ++nt) acc[nt] = (f32x4){0.f, 0.f, 0.f, 0.f};

    bf16x8 ring[8];
    #pragma unroll
    for (int f = 2 * LO - 7; f <= 2 * LO; ++f)
        ring[f & 7] = *(const bf16x8*)(bp + 16 * f);

    // 2-deep A prefetch (static names; no runtime-indexed arrays)
    bf16x8 aA = *(const bf16x8*)(ap + 32 * LO);
    bf16x8 aB = *(const bf16x8*)(ap + 32 * (LO + 1));

    #pragma unroll
    for (int sp = 0; sp < (HI - LO + 1) / 2; ++sp) {
        const int s0 = LO + 2 * sp;
        const int s1 = s0 + 1;
        if (s0 > LO) {
            ring[(2 * s0 - 1) & 7] = *(const bf16x8*)(bp + 16 * (2 * s0 - 1));
            ring[(2 * s0) & 7]     = *(const bf16x8*)(bp + 16 * (2 * s0));
        }
        #pragma unroll
        for (int nt = 0; nt < 8; ++nt)
            acc[nt] = __builtin_amdgcn_mfma_f32_16x16x32_bf16(
                aA, ring[(2 * s0 - nt) & 7], acc[nt], 0, 0, 0);
        if (s0 + 2 <= HI) aA = *(const bf16x8*)(ap + 32 * (s0 + 2));
        ring[(2 * s1 - 1) & 7] = *(const bf16x8*)(bp + 16 * (2 * s1 - 1));
        ring[(2 * s1) & 7]     = *(const bf16x8*)(bp + 16 * (2 * s1));
        #pragma unroll
        for (int nt = 0; nt < 8; ++nt)
            acc[nt] = __builtin_amdgcn_mfma_f32_16x16x32_bf16(
                aB, ring[(2 * s1 - nt) & 7], acc[nt], 0, 0, 0);
        if (s1 + 2 <= HI) aB = *(const bf16x8*)(ap + 32 * (s1 + 2));
    }

    // min/max over valid rows (C/D: col=lane&15, row=4*(lane>>4)+r)
    float mn = 3.4e38f, mx = -3.4e38f;
    #pragma unroll
    for (int nt = 0; nt < 8; ++nt)
        #pragma unroll
        for (int r = 0; r < 4; ++r)
            if (16 * t + 4 * g + r < NS) {
                const float v = acc[nt][r];
                mn = fminf(mn, v); mx = fmaxf(mx, v);
            }
    #pragma unroll
    for (int off = 32; off > 0; off >>= 1) {
        mn = fminf(mn, __shfl_down(mn, off));
        mx = fmaxf(mx, __shfl_down(mx, off));
    }
    if (lane == 0) { smn[wv] = mn; smx[wv] = mx; }

    __syncthreads();   // xSh dead (all waves past main loop); smn/smx visible

    // dump acc -> epi (f32), banks: n + 8g pattern -> 2-way (free)
    #pragma unroll
    for (int nt = 0; nt < 8; ++nt)
        #pragma unroll
        for (int r = 0; r < 4; ++r)
            epi[(4 * g + r) * EPS + wbase + 16 * nt + n] = acc[nt][r];
    __syncthreads();

    // horizontal bilinear 1024 -> 200 (jax semantics) for this tile's rows
    for (int idx = tid; idx < 16 * OW; idx += 512) {
        const int row16 = idx / OW;
        const int j = idx % OW;
        const int srow = 16 * t + row16;
        if (srow < NS) {
            const float xx = (j + 0.5f) * (1024.0f / 200.0f) - 0.5f;
            const float xf = floorf(xx);
            const float fx = xx - xf;
            int j0 = (int)xf, j1 = j0 + 1;
            j0 = max(0, min(NW - 1, j0)); j1 = max(0, min(NW - 1, j1));
            tmp[((size_t)b * NS + srow) * OW + j] = __float2bfloat16(
                (1.f - fx) * epi[row16 * EPS + j0] + fx * epi[row16 * EPS + j1]);
        }
    }

    // one plain store pair per block (disjoint slots, no init/atomics)
    if (tid == 0) {
        float bmn = smn[0], bmx = smx[0];
        #pragma unroll
        for (int w = 1; w < 8; ++w) {
            bmn = fminf(bmn, smn[w]);
            bmx = fmaxf(bmx, smx[w]);
        }
        mm[t * 256 + b] = bmn;
        mm[t * 256 + 128 + b] = bmx;
    }
}

// grid 896 = 7 classes x 128 batches; heavy classes (t=4,5,6: full s-range)
// dispatched first for backfill. LDS 66 KB -> 2 blocks/CU; VGPR target <=128.
__global__ __launch_bounds__(512, 4) void conv_mfma(
        const ushort* __restrict__ Kbf, const ushort* __restrict__ xRsh,
        __hip_bfloat16* __restrict__ tmp, float* __restrict__ mm) {
    __shared__ __align__(16) char smem[16 * EPS * 4];  // 66176 B (xSh 32896 overlaid)
    __shared__ float smn[8], smx[8];
    ushort* xSh = (ushort*)smem;
    float* epi = (float*)smem;

    const int cls = blockIdx.x >> 7;
    const int b = blockIdx.x & 127;
    const int t = (cls < 3) ? cls + 4 : 6 - cls;   // order: 4,5,6,3,2,1,0

    switch (t) {
        case 0: conv_body<12, 19>(t, b, Kbf, xRsh, tmp, mm, xSh, epi, smn, smx); break;
        case 1: conv_body< 9, 22>(t, b, Kbf, xRsh, tmp, mm, xSh, epi, smn, smx); break;
        case 2: conv_body< 6, 25>(t, b, Kbf, xRsh, tmp, mm, xSh, epi, smn, smx); break;
        case 3: conv_body< 3, 28>(t, b, Kbf, xRsh, tmp, mm, xSh, epi, smn, smx); break;
        default: conv_body<0, 31>(t, b, Kbf, xRsh, tmp, mm, xSh, epi, smn, smx); break;
    }
}

// vertical bilinear 101 -> 200 + normalize (jax semantics)
__global__ __launch_bounds__(256) void resize_v(
        const __hip_bfloat16* __restrict__ tmp, const float* __restrict__ mm,
        float* __restrict__ out) {
    int idx = blockIdx.x * 256 + threadIdx.x;
    if (idx >= NB * OH * OW) return;
    const int j = idx % OW;
    const int i = (idx / OW) % OH;
    const int b = idx / (OW * OH);
    float mn = mm[b], mx = mm[128 + b];
    #pragma unroll
    for (int t = 1; t < 7; ++t) {
        mn = fminf(mn, mm[t * 256 + b]);
        mx = fmaxf(mx, mm[t * 256 + 128 + b]);
    }
    const float inv = 1.0f / (mx - mn);
    const float y = (i + 0.5f) * (101.0f / 200.0f) - 0.5f;
    const float yf = floorf(y);
    const float fy = y - yf;
    int i0 = (int)yf, i1 = i0 + 1;
    i0 = max(0, min(NS - 1, i0)); i1 = max(0, min(NS - 1, i1));
    const __hip_bfloat16* tp = tmp + (size_t)b * NS * OW;
    const float v = (1.f - fy) * __bfloat162float(tp[i0 * OW + j])
                  + fy * __bfloat162float(tp[i1 * OW + j]);
    out[idx] = (v - mn) * inv;
}

extern "C" void kernel_launch(void* const* d_in, const int* in_sizes, int n_in,
                              void* d_out, int out_size, void* d_ws, size_t ws_size,
                              hipStream_t stream) {
    const float* x = (const float*)d_in[0];   // (128,1024) f32
    const float* K = (const float*)d_in[1];   // (101,1024) f32
    float* out = (float*)d_out;               // (128,200,200,1) f32

    char* ws = (char*)d_ws;
    float* mm = (float*)ws;                                  // 7168 B
    ushort* Kbf = (ushort*)(ws + 8192);                      // 229376 B
    ushort* xRsh = (ushort*)(ws + 8192 + 229376);            // 4210688 B
    __hip_bfloat16* tmp = (__hip_bfloat16*)(ws + 4448256);   // 5171200 B

    hipLaunchKernelGGL(prep_kernel, dim3(128), dim3(256), 0, stream, x, K, Kbf, xRsh);
    hipLaunchKernelGGL(conv_mfma, dim3(896), dim3(512), 0, stream, Kbf, xRsh, tmp, mm);
    const int t2 = NB * OH * OW;
    hipLaunchKernelGGL(resize_v, dim3((t2 + 255) / 256), dim3(256), 0, stream, tmp, mm, out);
}

// Round 7
// 99.339 us; speedup vs baseline: 1.1313x; 1.1313x over previous
//
#include <hip/hip_runtime.h>
#include <hip/hip_bf16.h>

#define NB 128
#define NS 101
#define NW 1024
#define OH 200
#define OW 200
#define EPS 1034   // epi row stride (floats): conflict-free acc dump

typedef __bf16 bf16x8 __attribute__((ext_vector_type(8)));
typedef float f32x4 __attribute__((ext_vector_type(4)));

// Active s-ranges per 16-row tile t (6*smax+2 truncation, verified r2-r6):
// t: 0[12,19] 1[9,22] 2[6,25] 3[3,28] 4[0,31] 5[0,31] 6[0,31]
// classA = t{0,1,3,4} -> 80 tiles, bases {0,8,22,48}; rows 0-31,48-79
// classB = t{2,5,6}   -> 84 tiles, bases {0,20,52};  rows 32-47,80-111

// Stage one K tile (f32 -> bf16 in-flight); rows >= NS are zeroed.
#define STAGE_T(t, lo, hi, base)                                              \
    _Pragma("unroll")                                                         \
    for (int s = (lo); s <= (hi); ++s) {                                      \
        if ((((base) + s - (lo)) & 7) == wv) {                                \
            const int row = 16 * (t) + n;                                     \
            union { ushort us[8]; uint4 v; } pk;                              \
            pk.v = (uint4){0u, 0u, 0u, 0u};                                   \
            if (row < NS) {                                                   \
                const float* kp = K + (size_t)row * NW + 32 * s + 8 * g;      \
                const float4 f0 = *(const float4*)kp;                         \
                const float4 f1 = *(const float4*)(kp + 4);                   \
                __hip_bfloat16 h;                                             \
                h = __float2bfloat16(f0.x); pk.us[0] = reinterpret_cast<const ushort&>(h); \
                h = __float2bfloat16(f0.y); pk.us[1] = reinterpret_cast<const ushort&>(h); \
                h = __float2bfloat16(f0.z); pk.us[2] = reinterpret_cast<const ushort&>(h); \
                h = __float2bfloat16(f0.w); pk.us[3] = reinterpret_cast<const ushort&>(h); \
                h = __float2bfloat16(f1.x); pk.us[4] = reinterpret_cast<const ushort&>(h); \
                h = __float2bfloat16(f1.y); pk.us[5] = reinterpret_cast<const ushort&>(h); \
                h = __float2bfloat16(f1.z); pk.us[6] = reinterpret_cast<const ushort&>(h); \
                h = __float2bfloat16(f1.w); pk.us[7] = reinterpret_cast<const ushort&>(h); \
            }                                                                 \
            *(uint4*)&A_lds[((base) + s - (lo)) * 512 + lane * 8] = pk.v;     \
        }                                                                     \
    }

// One MFMA tile-step at s = 4*grp + i (i LITERAL): all ring indices static.
#define MFMA_T(t, lo, hi, base, ti, i)                                        \
    if (s >= (lo) && s <= (hi)) {                                             \
        bf16x8 af = *(const bf16x8*)&A_lds[((base) + s - (lo)) * 512 + lane * 8]; \
        _Pragma("unroll")                                                     \
        for (int nt = 0; nt < 8; ++nt)                                        \
            acc[ti][nt] = __builtin_amdgcn_mfma_f32_16x16x32_bf16(            \
                af, ring[(2 * (i) - nt) & 7], acc[ti][nt], 0, 0, 0);          \
    }

// Epilogue per t-tile: dump acc -> epi LDS (f32), track min/max, then
// horizontal bilinear 1024 -> 200 from LDS, write bf16 tmp[b][srow][200].
#define EPI_T(t, ti)                                                          \
    {                                                                         \
        _Pragma("unroll")                                                     \
        for (int nt = 0; nt < 8; ++nt) {                                      \
            _Pragma("unroll")                                                 \
            for (int r = 0; r < 4; ++r) {                                     \
                const int row16 = 4 * g + r;                                  \
                float v = acc[ti][nt][r];                                     \
                if (16 * (t) + row16 < NS) { mn = fminf(mn, v); mx = fmaxf(mx, v); } \
                epi[row16 * EPS + wbase + 16 * nt + n] = v;                   \
            }                                                                 \
        }                                                                     \
        __syncthreads();                                                      \
        for (int idx = tid; idx < 16 * OW; idx += 512) {                      \
            const int row16 = idx / OW;                                       \
            const int j = idx % OW;                                           \
            const int srow = 16 * (t) + row16;                                \
            if (srow < NS) {                                                  \
                const float xx = (j + 0.5f) * (1024.0f / 200.0f) - 0.5f;      \
                const float xf = floorf(xx);                                  \
                const float fx = xx - xf;                                     \
                int j0 = (int)xf, j1 = j0 + 1;                                \
                j0 = max(0, min(NW - 1, j0)); j1 = max(0, min(NW - 1, j1));   \
                tmp[((size_t)b * NS + srow) * OW + j] = __float2bfloat16(     \
                    (1.f - fx) * epi[row16 * EPS + j0] + fx * epi[row16 * EPS + j1]); \
            }                                                                 \
        }                                                                     \
        __syncthreads();                                                      \
    }

// Ring refill at s = 4*grp + i (i LITERAL): slots (2i-1)&7, (2i)&7 static.
#define RING_FILL(i)                                                          \
    if (s > 0) {                                                              \
        ring[(2 * (i) - 1) & 7] = *(const bf16x8*)(bp + 16 * (2 * s - 1));    \
        ring[(2 * (i)) & 7]     = *(const bf16x8*)(bp + 16 * (2 * s));        \
    }

// grid 256: bid<128 -> classA batch bid; bid>=128 -> classB batch bid-128.
// 512 threads = 8 waves; wave wv owns w in [wv*128, wv*128+128).
// mm layout (plain f32 stores, disjoint per block, no init needed):
//   mm[cls*256 + b] = min, mm[cls*256 + 128 + b] = max.
__global__ __launch_bounds__(512, 1) void conv_mfma(
        const float* __restrict__ x, const float* __restrict__ K,
        __hip_bfloat16* __restrict__ tmp, float* __restrict__ mm) {
    // overlay: main phase {A_lds 86016B | xSh 32896B}; epilogue {epi 66176B}
    __shared__ __align__(16) char smem[118912];
    ushort* A_lds = (ushort*)smem;
    ushort* xSh = (ushort*)(smem + 86016);
    float* epi = (float*)smem;
    __shared__ float smn[8], smx[8];

    const int tid = threadIdx.x;
    const int bid = blockIdx.x;
    const int cls = bid >> 7;
    const int b = bid & 127;
    const int wv = tid >> 6;
    const int lane = tid & 63;
    const int n = lane & 15;
    const int g = lane >> 4;

    // ---- stage reversed padded signal, 8 shifted copies: xSh[d][i]=xR[i+d],
    //      xR[q] = x[1535-q] for q in [512,1536) else 0 ----
    {
        const float* xb = x + (size_t)b * NW;
        for (int idx = tid; idx < 8 * 257; idx += 512) {
            int dlt = idx / 257;
            int i0 = (idx % 257) * 8;
            union { ushort us[8]; uint4 v; } pk;
            #pragma unroll
            for (int j = 0; j < 8; ++j) {
                int ir = i0 + j + dlt;
                float f = (ir >= 512 && ir < 1536) ? xb[1535 - ir] : 0.0f;
                __hip_bfloat16 h = __float2bfloat16(f);
                pk.us[j] = reinterpret_cast<const ushort&>(h);
            }
            *reinterpret_cast<uint4*>(&xSh[dlt * 2056 + i0]) = pk.v;
        }
    }

    // ---- stage A tiles (f32 K -> bf16 LDS, once per block) ----
    if (cls == 0) {
        STAGE_T(0, 12, 19, 0)
        STAGE_T(1,  9, 22, 8)
        STAGE_T(3,  3, 28, 22)
        STAGE_T(4,  0, 31, 48)
    } else {
        STAGE_T(2,  6, 25, 0)
        STAGE_T(5,  0, 31, 20)
        STAGE_T(6,  0, 31, 52)
    }
    __syncthreads();   // all ds_writes (A_lds + xSh) visible

    // ---- B-ring base: lane reads xR[q0..q0+7], q0 = 1023-wbase-n+8g+16f,
    //      from shifted copy dlt=(7-n)&7 (16B-aligned by construction) ----
    const int dlt = (7 - n) & 7;
    const int wbase = wv * 128;
    const ushort* bp = xSh + dlt * 2056 + (1023 - wbase - n + 8 * g - dlt);

    float mn = 3.4e38f, mx = -3.4e38f;

    if (cls == 0) {
        f32x4 acc[4][8];
        #pragma unroll
        for (int ti = 0; ti < 4; ++ti)
            #pragma unroll
            for (int nt = 0; nt < 8; ++nt)
                acc[ti][nt] = (f32x4){0.f, 0.f, 0.f, 0.f};
        bf16x8 ring[8];
        #pragma unroll
        for (int f = -7; f <= 0; ++f)
            ring[f & 7] = *(const bf16x8*)(bp + 16 * f);
        // runtime group loop x fully-static inner 4 steps: ring indices
        // have period 4 in s, so all register indices are literals.
        for (int grp = 0; grp < 8; ++grp) {
            #pragma unroll
            for (int i = 0; i < 4; ++i) {
                const int s = 4 * grp + i;
                RING_FILL(i)
                MFMA_T(0, 12, 19, 0, 0, i)
                MFMA_T(1,  9, 22, 8, 1, i)
                MFMA_T(3,  3, 28, 22, 2, i)
                MFMA_T(4,  0, 31, 48, 3, i)
            }
        }
        __syncthreads();   // all waves done with A_lds/xSh before epi overlay
        EPI_T(0, 0)
        EPI_T(1, 1)
        EPI_T(3, 2)
        EPI_T(4, 3)
    } else {
        f32x4 acc[3][8];
        #pragma unroll
        for (int ti = 0; ti < 3; ++ti)
            #pragma unroll
            for (int nt = 0; nt < 8; ++nt)
                acc[ti][nt] = (f32x4){0.f, 0.f, 0.f, 0.f};
        bf16x8 ring[8];
        #pragma unroll
        for (int f = -7; f <= 0; ++f)
            ring[f & 7] = *(const bf16x8*)(bp + 16 * f);
        for (int grp = 0; grp < 8; ++grp) {
            #pragma unroll
            for (int i = 0; i < 4; ++i) {
                const int s = 4 * grp + i;
                RING_FILL(i)
                MFMA_T(2,  6, 25, 0, 0, i)
                MFMA_T(5,  0, 31, 20, 1, i)
                MFMA_T(6,  0, 31, 52, 2, i)
            }
        }
        __syncthreads();
        EPI_T(2, 0)
        EPI_T(5, 1)
        EPI_T(6, 2)
    }

    // block-level min/max reduce, one plain store pair per block (no atomics)
    #pragma unroll
    for (int off = 32; off > 0; off >>= 1) {
        mn = fminf(mn, __shfl_down(mn, off));
        mx = fmaxf(mx, __shfl_down(mx, off));
    }
    if (lane == 0) { smn[wv] = mn; smx[wv] = mx; }
    __syncthreads();
    if (tid == 0) {
        float bmn = smn[0], bmx = smx[0];
        #pragma unroll
        for (int w = 1; w < 8; ++w) {
            bmn = fminf(bmn, smn[w]);
            bmx = fmaxf(bmx, smx[w]);
        }
        mm[cls * 256 + b] = bmn;
        mm[cls * 256 + 128 + b] = bmx;
    }
}

// vertical bilinear 101 -> 200 + normalize (jax semantics)
__global__ __launch_bounds__(256) void resize_v(
        const __hip_bfloat16* __restrict__ tmp, const float* __restrict__ mm,
        float* __restrict__ out) {
    int idx = blockIdx.x * 256 + threadIdx.x;
    if (idx >= NB * OH * OW) return;
    const int j = idx % OW;
    const int i = (idx / OW) % OH;
    const int b = idx / (OW * OH);
    const float mn = fminf(mm[b], mm[256 + b]);
    const float mx = fmaxf(mm[128 + b], mm[384 + b]);
    const float inv = 1.0f / (mx - mn);
    const float y = (i + 0.5f) * (101.0f / 200.0f) - 0.5f;
    const float yf = floorf(y);
    const float fy = y - yf;
    int i0 = (int)yf, i1 = i0 + 1;
    i0 = max(0, min(NS - 1, i0)); i1 = max(0, min(NS - 1, i1));
    const __hip_bfloat16* tp = tmp + (size_t)b * NS * OW;
    float v = (1.f - fy) * __bfloat162float(tp[i0 * OW + j])
            + fy * __bfloat162float(tp[i1 * OW + j]);
    out[idx] = (v - mn) * inv;
}

extern "C" void kernel_launch(void* const* d_in, const int* in_sizes, int n_in,
                              void* d_out, int out_size, void* d_ws, size_t ws_size,
                              hipStream_t stream) {
    const float* x = (const float*)d_in[0];   // (128,1024) f32
    const float* K = (const float*)d_in[1];   // (101,1024) f32
    float* out = (float*)d_out;               // (128,200,200,1) f32

    char* ws = (char*)d_ws;
    float* mm = (float*)ws;                               // 2 KB (512 f32)
    __hip_bfloat16* tmp = (__hip_bfloat16*)(ws + 4096);   // 5.17 MB

    hipLaunchKernelGGL(conv_mfma, dim3(256), dim3(512), 0, stream, x, K, tmp, mm);
    const int t2 = NB * OH * OW;
    hipLaunchKernelGGL(resize_v, dim3((t2 + 255) / 256), dim3(256), 0, stream, tmp, mm, out);
}

// Round 8
// 97.011 us; speedup vs baseline: 1.1584x; 1.0240x over previous
//
#include <hip/hip_runtime.h>
#include <hip/hip_bf16.h>

#define NB 128
#define NS 101
#define NW 1024
#define OH 200
#define OW 200
#define EPS 1034   // epi row stride (floats): 2-way (free) acc dump

typedef __bf16 bf16x8 __attribute__((ext_vector_type(8)));
typedef float f32x4 __attribute__((ext_vector_type(4)));

// Active s-ranges per 16-row tile t (6*smax+2 truncation, verified r2-r7):
// t: 0[12,19] 1[9,22] 2[6,25] 3[3,28] 4[0,31] 5[0,31] 6[0,31]
// classA = t{0,1,3,4} -> 80 tiles, bases {0,8,22,48}; rows 0-31,48-79
// classB = t{2,5,6}   -> 84 tiles, bases {0,20,52};  rows 32-47,80-111

// Stage one K tile (f32 -> bf16 in-flight); rows >= NS are zeroed.
// 16 waves share the staging: tile idx & 15 == wv.
#define STAGE_T(t, lo, hi, base)                                              \
    _Pragma("unroll")                                                         \
    for (int s = (lo); s <= (hi); ++s) {                                      \
        if ((((base) + s - (lo)) & 15) == wv) {                               \
            const int row = 16 * (t) + n;                                     \
            union { ushort us[8]; uint4 v; } pk;                              \
            pk.v = (uint4){0u, 0u, 0u, 0u};                                   \
            if (row < NS) {                                                   \
                const float* kp = K + (size_t)row * NW + 32 * s + 8 * g;      \
                const float4 f0 = *(const float4*)kp;                         \
                const float4 f1 = *(const float4*)(kp + 4);                   \
                __hip_bfloat16 h;                                             \
                h = __float2bfloat16(f0.x); pk.us[0] = reinterpret_cast<const ushort&>(h); \
                h = __float2bfloat16(f0.y); pk.us[1] = reinterpret_cast<const ushort&>(h); \
                h = __float2bfloat16(f0.z); pk.us[2] = reinterpret_cast<const ushort&>(h); \
                h = __float2bfloat16(f0.w); pk.us[3] = reinterpret_cast<const ushort&>(h); \
                h = __float2bfloat16(f1.x); pk.us[4] = reinterpret_cast<const ushort&>(h); \
                h = __float2bfloat16(f1.y); pk.us[5] = reinterpret_cast<const ushort&>(h); \
                h = __float2bfloat16(f1.z); pk.us[6] = reinterpret_cast<const ushort&>(h); \
                h = __float2bfloat16(f1.w); pk.us[7] = reinterpret_cast<const ushort&>(h); \
            }                                                                 \
            *(uint4*)&A_lds[((base) + s - (lo)) * 512 + lane * 8] = pk.v;     \
        }                                                                     \
    }

// One MFMA tile-step at compile-time s: ring slot (2s-nt)&3 folds.
#define MFMA_T(t, lo, hi, base, ti)                                           \
    if (s >= (lo) && s <= (hi)) {                                             \
        bf16x8 af = *(const bf16x8*)&A_lds[((base) + s - (lo)) * 512 + lane * 8]; \
        _Pragma("unroll")                                                     \
        for (int nt = 0; nt < 4; ++nt)                                        \
            acc[ti][nt] = __builtin_amdgcn_mfma_f32_16x16x32_bf16(            \
                af, ring[(2 * s - nt) & 3], acc[ti][nt], 0, 0, 0);            \
    }

// Epilogue per t-tile: dump acc -> epi LDS (f32), track min/max, then
// horizontal bilinear 1024 -> 200 from LDS, write bf16 tmp[b][srow][200].
#define EPI_T(t, ti)                                                          \
    {                                                                         \
        _Pragma("unroll")                                                     \
        for (int nt = 0; nt < 4; ++nt) {                                      \
            _Pragma("unroll")                                                 \
            for (int r = 0; r < 4; ++r) {                                     \
                const int row16 = 4 * g + r;                                  \
                float v = acc[ti][nt][r];                                     \
                if (16 * (t) + row16 < NS) { mn = fminf(mn, v); mx = fmaxf(mx, v); } \
                epi[row16 * EPS + wbase + 16 * nt + n] = v;                   \
            }                                                                 \
        }                                                                     \
        __syncthreads();                                                      \
        for (int idx = tid; idx < 16 * OW; idx += 1024) {                     \
            const int row16 = idx / OW;                                       \
            const int j = idx % OW;                                           \
            const int srow = 16 * (t) + row16;                                \
            if (srow < NS) {                                                  \
                const float xx = (j + 0.5f) * (1024.0f / 200.0f) - 0.5f;      \
                const float xf = floorf(xx);                                  \
                const float fx = xx - xf;                                     \
                int j0 = (int)xf, j1 = j0 + 1;                                \
                j0 = max(0, min(NW - 1, j0)); j1 = max(0, min(NW - 1, j1));   \
                tmp[((size_t)b * NS + srow) * OW + j] = __float2bfloat16(     \
                    (1.f - fx) * epi[row16 * EPS + j0] + fx * epi[row16 * EPS + j1]); \
            }                                                                 \
        }                                                                     \
        __syncthreads();                                                      \
    }

// Ring refill (compile-time s): slots (2s-1)&3, (2s)&3; f=2s-5,2s-4 retired.
#define RING_FILL                                                             \
    if (s > 0) {                                                              \
        ring[(2 * s - 1) & 3] = *(const bf16x8*)(bp + 16 * (2 * s - 1));      \
        ring[(2 * s) & 3]     = *(const bf16x8*)(bp + 16 * (2 * s));          \
    }

// grid 256: bid<128 -> classA batch bid; bid>=128 -> classB batch bid-128.
// 1024 threads = 16 waves (4/SIMD); wave wv owns w in [wv*64, wv*64+64).
// mm layout (plain f32 stores, disjoint per block, no init needed):
//   mm[cls*256 + b] = min, mm[cls*256 + 128 + b] = max.
__global__ __launch_bounds__(1024, 4) void conv_mfma(
        const float* __restrict__ x, const float* __restrict__ K,
        __hip_bfloat16* __restrict__ tmp, float* __restrict__ mm) {
    // overlay: main phase {A_lds 86016B | xSh 32896B}; epilogue {epi 66176B}
    __shared__ __align__(16) char smem[118912];
    ushort* A_lds = (ushort*)smem;
    ushort* xSh = (ushort*)(smem + 86016);
    float* epi = (float*)smem;
    __shared__ float smn[16], smx[16];

    const int tid = threadIdx.x;
    const int bid = blockIdx.x;
    const int cls = bid >> 7;
    const int b = bid & 127;
    const int wv = tid >> 6;
    const int lane = tid & 63;
    const int n = lane & 15;
    const int g = lane >> 4;

    // ---- stage reversed padded signal, 8 shifted copies: xSh[d][i]=xR[i+d],
    //      xR[q] = x[1535-q] for q in [512,1536) else 0 ----
    {
        const float* xb = x + (size_t)b * NW;
        for (int idx = tid; idx < 8 * 257; idx += 1024) {
            int dlt = idx / 257;
            int i0 = (idx % 257) * 8;
            union { ushort us[8]; uint4 v; } pk;
            #pragma unroll
            for (int j = 0; j < 8; ++j) {
                int ir = i0 + j + dlt;
                float f = (ir >= 512 && ir < 1536) ? xb[1535 - ir] : 0.0f;
                __hip_bfloat16 h = __float2bfloat16(f);
                pk.us[j] = reinterpret_cast<const ushort&>(h);
            }
            *reinterpret_cast<uint4*>(&xSh[dlt * 2056 + i0]) = pk.v;
        }
    }

    // ---- stage A tiles (f32 K -> bf16 LDS, once per block) ----
    if (cls == 0) {
        STAGE_T(0, 12, 19, 0)
        STAGE_T(1,  9, 22, 8)
        STAGE_T(3,  3, 28, 22)
        STAGE_T(4,  0, 31, 48)
    } else {
        STAGE_T(2,  6, 25, 0)
        STAGE_T(5,  0, 31, 20)
        STAGE_T(6,  0, 31, 52)
    }
    __syncthreads();   // all ds_writes (A_lds + xSh) visible

    // ---- B-ring base: lane reads xR[q0..q0+7], q0 = 1023-wbase-n+8g+16f,
    //      from shifted copy dlt=(7-n)&7 (16B-aligned by construction) ----
    const int dlt = (7 - n) & 7;
    const int wbase = wv * 64;
    const ushort* bp = xSh + dlt * 2056 + (1023 - wbase - n + 8 * g - dlt);

    float mn = 3.4e38f, mx = -3.4e38f;

    if (cls == 0) {
        f32x4 acc[4][4];
        #pragma unroll
        for (int ti = 0; ti < 4; ++ti)
            #pragma unroll
            for (int nt = 0; nt < 4; ++nt)
                acc[ti][nt] = (f32x4){0.f, 0.f, 0.f, 0.f};
        bf16x8 ring[4];
        #pragma unroll
        for (int f = -3; f <= 0; ++f)
            ring[f & 3] = *(const bf16x8*)(bp + 16 * f);
        #pragma unroll
        for (int s = 0; s < 32; ++s) {
            RING_FILL
            MFMA_T(0, 12, 19, 0, 0)
            MFMA_T(1,  9, 22, 8, 1)
            MFMA_T(3,  3, 28, 22, 2)
            MFMA_T(4,  0, 31, 48, 3)
        }
        __syncthreads();   // all waves done with A_lds/xSh before epi overlay
        EPI_T(0, 0)
        EPI_T(1, 1)
        EPI_T(3, 2)
        EPI_T(4, 3)
    } else {
        f32x4 acc[3][4];
        #pragma unroll
        for (int ti = 0; ti < 3; ++ti)
            #pragma unroll
            for (int nt = 0; nt < 4; ++nt)
                acc[ti][nt] = (f32x4){0.f, 0.f, 0.f, 0.f};
        bf16x8 ring[4];
        #pragma unroll
        for (int f = -3; f <= 0; ++f)
            ring[f & 3] = *(const bf16x8*)(bp + 16 * f);
        #pragma unroll
        for (int s = 0; s < 32; ++s) {
            RING_FILL
            MFMA_T(2,  6, 25, 0, 0)
            MFMA_T(5,  0, 31, 20, 1)
            MFMA_T(6,  0, 31, 52, 2)
        }
        __syncthreads();
        EPI_T(2, 0)
        EPI_T(5, 1)
        EPI_T(6, 2)
    }

    // block-level min/max reduce, one plain store pair per block (no atomics)
    #pragma unroll
    for (int off = 32; off > 0; off >>= 1) {
        mn = fminf(mn, __shfl_down(mn, off));
        mx = fmaxf(mx, __shfl_down(mx, off));
    }
    if (lane == 0) { smn[wv] = mn; smx[wv] = mx; }
    __syncthreads();
    if (tid == 0) {
        float bmn = smn[0], bmx = smx[0];
        #pragma unroll
        for (int w = 1; w < 16; ++w) {
            bmn = fminf(bmn, smn[w]);
            bmx = fmaxf(bmx, smx[w]);
        }
        mm[cls * 256 + b] = bmn;
        mm[cls * 256 + 128 + b] = bmx;
    }
}

// vertical bilinear 101 -> 200 + normalize (jax semantics)
__global__ __launch_bounds__(256) void resize_v(
        const __hip_bfloat16* __restrict__ tmp, const float* __restrict__ mm,
        float* __restrict__ out) {
    int idx = blockIdx.x * 256 + threadIdx.x;
    if (idx >= NB * OH * OW) return;
    const int j = idx % OW;
    const int i = (idx / OW) % OH;
    const int b = idx / (OW * OH);
    const float mn = fminf(mm[b], mm[256 + b]);
    const float mx = fmaxf(mm[128 + b], mm[384 + b]);
    const float inv = 1.0f / (mx - mn);
    const float y = (i + 0.5f) * (101.0f / 200.0f) - 0.5f;
    const float yf = floorf(y);
    const float fy = y - yf;
    int i0 = (int)yf, i1 = i0 + 1;
    i0 = max(0, min(NS - 1, i0)); i1 = max(0, min(NS - 1, i1));
    const __hip_bfloat16* tp = tmp + (size_t)b * NS * OW;
    float v = (1.f - fy) * __bfloat162float(tp[i0 * OW + j])
            + fy * __bfloat162float(tp[i1 * OW + j]);
    out[idx] = (v - mn) * inv;
}

extern "C" void kernel_launch(void* const* d_in, const int* in_sizes, int n_in,
                              void* d_out, int out_size, void* d_ws, size_t ws_size,
                              hipStream_t stream) {
    const float* x = (const float*)d_in[0];   // (128,1024) f32
    const float* K = (const float*)d_in[1];   // (101,1024) f32
    float* out = (float*)d_out;               // (128,200,200,1) f32

    char* ws = (char*)d_ws;
    float* mm = (float*)ws;                               // 2 KB (512 f32)
    __hip_bfloat16* tmp = (__hip_bfloat16*)(ws + 4096);   // 5.17 MB

    hipLaunchKernelGGL(conv_mfma, dim3(256), dim3(1024), 0, stream, x, K, tmp, mm);
    const int t2 = NB * OH * OW;
    hipLaunchKernelGGL(resize_v, dim3((t2 + 255) / 256), dim3(256), 0, stream, tmp, mm, out);
}